// Round 1
// baseline (49097.296 us; speedup 1.0000x reference)
//
#include <hip/hip_runtime.h>
#include <math.h>

#define HH 256
#define NSUB 4
#define DD 64
#define HDIM 64
#define TSTEPS 512
#define DIN 128
#define EPSR 1e-8f

__device__ __forceinline__ float sigmoidf_(float v) { return 1.0f / (1.0f + expf(-v)); }

extern "C" __global__ __launch_bounds__(256)
void xlstm_seq(const float* __restrict__ x,
               const float* __restrict__ W_in, const float* __restrict__ b_in,
               const float* __restrict__ Wih, const float* __restrict__ bih,
               const float* __restrict__ Whh,
               const float* __restrict__ Wq, const float* __restrict__ bq,
               const float* __restrict__ Wk, const float* __restrict__ bk,
               const float* __restrict__ Wv, const float* __restrict__ bv,
               const float* __restrict__ Wi, const float* __restrict__ bi,
               const float* __restrict__ Wf, const float* __restrict__ bf,
               const float* __restrict__ Wo, const float* __restrict__ bo,
               const float* __restrict__ Wp, const float* __restrict__ bp,
               const float* __restrict__ sWih, const float* __restrict__ sbih,
               const float* __restrict__ sWhh, const float* __restrict__ sfb,
               const float* __restrict__ aW1, const float* __restrict__ ab1,
               const float* __restrict__ aW2, const float* __restrict__ ab2,
               const float* __restrict__ lng, const float* __restrict__ lnb,
               float* __restrict__ out)
{
    const int b = blockIdx.x;
    const int t = threadIdx.x;          // 0..255 -> owns hidden index t
    const int s = t >> 6;               // subspace id (wave id)
    const int d = t & 63;               // index within subspace / lane

    __shared__ float xbuf[DIN];
    __shared__ float xt_l[HH];
    __shared__ float h0_l[HH];
    __shared__ float x1_l[HH];
    __shared__ float x2_l[HH];
    __shared__ float hs_l[HH];
    __shared__ float qb[HDIM], kb[HDIM], vb[HDIM];
    __shared__ float ht_l[HDIM];
    __shared__ float Cm[HDIM * 65];     // 64x64 padded to stride 65 (bank-conflict-free)
    __shared__ float sc_l[8];           // [0]=i1 [1]=f1 [4..7]=attention scores
    __shared__ float hfb[HH];

    // ---- state init ----
    float c0 = 0.f, n0 = 1.f;           // layer-0 sLSTM state at index t
    float cs = 0.f, ns = 1.f;           // subspace sLSTM state at (s,d)
    float n1 = 1.f;                     // mLSTM normalizer (replicated per thread)
    h0_l[t] = 0.f;
    hs_l[t] = 0.f;
    for (int e = t; e < HDIM * 65; e += 256) Cm[e] = 0.f;
    __syncthreads();

    const float* xb = x + (size_t)b * TSTEPS * DIN;

    for (int tt = 0; tt < TSTEPS; ++tt) {
        // ---- stage 1: load input row ----
        if (t < DIN) xbuf[t] = xb[tt * DIN + t];
        __syncthreads();

        // ---- stage 2: xt = x @ W_in + b_in ----
        float xtv = b_in[t];
        #pragma unroll 4
        for (int j = 0; j < DIN; ++j) xtv += xbuf[j] * W_in[j * HH + t];
        xt_l[t] = xtv;
        __syncthreads();

        // ---- stage 3: layer-0 sLSTM gates = xt@Wih + bih + h0@Whh ----
        float g0 = bih[t], g1 = bih[HH + t], g2 = bih[2 * HH + t], g3 = bih[3 * HH + t];
        #pragma unroll 4
        for (int j = 0; j < HH; ++j) {
            float xj = xt_l[j], hj = h0_l[j];
            const float* wi = Wih + j * 4 * HH + t;
            const float* wh = Whh + j * 4 * HH + t;
            g0 += xj * wi[0]      + hj * wh[0];
            g1 += xj * wi[HH]     + hj * wh[HH];
            g2 += xj * wi[2 * HH] + hj * wh[2 * HH];
            g3 += xj * wi[3 * HH] + hj * wh[3 * HH];
        }
        float i0 = expf(g0);
        float f0 = sigmoidf_(g1);
        float o0 = sigmoidf_(g2);
        float cn = f0 * c0 + i0 * tanhf(g3);
        float nn = f0 * n0 + i0;
        float h0n = o0 * tanhf(cn / (nn + EPSR));
        c0 = cn; n0 = nn;
        float x1v = h0n + xtv;
        __syncthreads();                 // all reads of h0_l / xt_l done
        h0_l[t] = h0n;
        x1_l[t] = x1v;
        __syncthreads();

        // ---- stage 4: q, k, v, i1, f1 ----
        if (t < 64) {
            float a = bq[t];
            #pragma unroll 4
            for (int j = 0; j < HH; ++j) a += x1_l[j] * Wq[j * HDIM + t];
            qb[t] = a;
        } else if (t < 128) {
            float a = bk[d];
            #pragma unroll 4
            for (int j = 0; j < HH; ++j) a += x1_l[j] * Wk[j * HDIM + d];
            kb[d] = a;
        } else if (t < 192) {
            float a = bv[d];
            #pragma unroll 4
            for (int j = 0; j < HH; ++j) a += x1_l[j] * Wv[j * HDIM + d];
            vb[d] = a;
        } else {
            // wave 3: i1/f1 scalar projections via wave reduction
            float pi = 0.f, pf = 0.f;
            int j0 = d * 4;
            #pragma unroll
            for (int j = j0; j < j0 + 4; ++j) { pi += x1_l[j] * Wi[j]; pf += x1_l[j] * Wf[j]; }
            for (int off = 32; off > 0; off >>= 1) {
                pi += __shfl_down(pi, off);
                pf += __shfl_down(pf, off);
            }
            if (d == 0) { sc_l[0] = expf(pi + bi[0]); sc_l[1] = sigmoidf_(pf + bf[0]); }
        }
        __syncthreads();

        // ---- stage 5: C update, o-preact, n1 ----
        float i1 = sc_l[0], f1 = sc_l[1];
        {
            int ir = t >> 2;             // C row
            int j0 = (t & 3) * 16;       // quarter-row
            float vi = vb[ir];
            #pragma unroll
            for (int e = 0; e < 16; ++e) {
                int j = j0 + e;
                Cm[ir * 65 + j] = f1 * Cm[ir * 65 + j] + i1 * vi * kb[j];
            }
        }
        n1 = f1 * n1 + i1;
        float opre = bo[t];
        #pragma unroll 4
        for (int j = 0; j < HH; ++j) opre += x1_l[j] * Wo[j * HH + t];
        __syncthreads();

        // ---- stage 6: Cq / h_tilde ----
        if (t < 64) {
            float a = 0.f;
            #pragma unroll 8
            for (int j = 0; j < HDIM; ++j) a += Cm[t * 65 + j] * qb[j];
            ht_l[t] = a / (n1 + EPSR);
        }
        __syncthreads();

        // ---- stage 7: h1 = o1 * tanh(ht@Wp + bp); x2 = h1 + x1 ----
        float pp = bp[t];
        #pragma unroll 4
        for (int j = 0; j < HDIM; ++j) pp += ht_l[j] * Wp[j * HH + t];
        float h1n = sigmoidf_(opre) * tanhf(pp);
        float x2v = h1n + x1v;
        x2_l[t] = x2v;
        __syncthreads();

        // ---- stage 8: subspace sLSTM gates ----
        float sg0 = sbih[s * 256 + d],       sg1 = sbih[s * 256 + 64 + d],
              sg2 = sbih[s * 256 + 128 + d], sg3 = sbih[s * 256 + 192 + d];
        {
            const float* wi = sWih + s * 64 * 256 + d;
            const float* wh = sWhh + s * 64 * 256 + d;
            #pragma unroll 4
            for (int j = 0; j < DD; ++j) {
                float xj = x2_l[s * 64 + j], hj = hs_l[s * 64 + j];
                const float* wij = wi + j * 256;
                const float* whj = wh + j * 256;
                sg0 += xj * wij[0]   + hj * whj[0];
                sg1 += xj * wij[64]  + hj * whj[64];
                sg2 += xj * wij[128] + hj * whj[128];
                sg3 += xj * wij[192] + hj * whj[192];
            }
        }
        float si = expf(sg0);
        float sf = sigmoidf_(sg1 + sfb[s * 64 + d]);
        float so = sigmoidf_(sg2);
        float csn = sf * cs + si * tanhf(sg3);
        float nsn = sf * ns + si;
        float hsn = so * tanhf(csn / (nsn + EPSR));
        cs = csn; ns = nsn;
        __syncthreads();                 // readers of hs_l done
        hs_l[t] = hsn;
        __syncthreads();

        // ---- final step only: attention fusion + layernorm + output ----
        if (tt == TSTEPS - 1) {
            float av = ab1[d];
            #pragma unroll 4
            for (int j = 0; j < DD; ++j) av += hs_l[s * 64 + j] * aW1[j * 64 + d];
            float contrib = tanhf(av) * aW2[d];
            for (int off = 32; off > 0; off >>= 1) contrib += __shfl_down(contrib, off);
            if (d == 0) sc_l[4 + s] = contrib + ab2[0];
            __syncthreads();
            float a0 = sc_l[4], a1 = sc_l[5], a2 = sc_l[6], a3 = sc_l[7];
            float m = fmaxf(fmaxf(a0, a1), fmaxf(a2, a3));
            float e0 = expf(a0 - m), e1 = expf(a1 - m), e2 = expf(a2 - m), e3 = expf(a3 - m);
            float inv = 1.f / (e0 + e1 + e2 + e3);
            float hf = (e0 * hs_l[d] + e1 * hs_l[64 + d] + e2 * hs_l[128 + d] + e3 * hs_l[192 + d]) * inv;
            hfb[t] = hf;
            __syncthreads();
            float mu = 0.f;
            for (int j = 0; j < HH; ++j) mu += hfb[j];
            mu *= (1.0f / HH);
            float var = 0.f;
            for (int j = 0; j < HH; ++j) { float dv = hfb[j] - mu; var += dv * dv; }
            var *= (1.0f / HH);
            float outv = (hf - mu) / sqrtf(var + 1e-5f) * lng[t] + lnb[t];
            out[b * HH + t] = outv;
        }
    }
}

extern "C" void kernel_launch(void* const* d_in, const int* in_sizes, int n_in,
                              void* d_out, int out_size, void* d_ws, size_t ws_size,
                              hipStream_t stream) {
    (void)in_sizes; (void)n_in; (void)d_ws; (void)ws_size; (void)out_size;
    const float* x     = (const float*)d_in[0];
    const float* W_in  = (const float*)d_in[1];
    const float* b_in  = (const float*)d_in[2];
    const float* Wih   = (const float*)d_in[3];
    const float* bih   = (const float*)d_in[4];
    const float* Whh   = (const float*)d_in[5];
    const float* Wq    = (const float*)d_in[6];
    const float* bq    = (const float*)d_in[7];
    const float* Wk    = (const float*)d_in[8];
    const float* bk    = (const float*)d_in[9];
    const float* Wv    = (const float*)d_in[10];
    const float* bv    = (const float*)d_in[11];
    const float* Wi    = (const float*)d_in[12];
    const float* bi    = (const float*)d_in[13];
    const float* Wf    = (const float*)d_in[14];
    const float* bf    = (const float*)d_in[15];
    const float* Wo    = (const float*)d_in[16];
    const float* bo    = (const float*)d_in[17];
    const float* Wp    = (const float*)d_in[18];
    const float* bp    = (const float*)d_in[19];
    const float* sWih  = (const float*)d_in[20];
    const float* sbih  = (const float*)d_in[21];
    const float* sWhh  = (const float*)d_in[22];
    const float* sfb   = (const float*)d_in[23];
    const float* aW1   = (const float*)d_in[24];
    const float* ab1   = (const float*)d_in[25];
    const float* aW2   = (const float*)d_in[26];
    const float* ab2   = (const float*)d_in[27];
    const float* lng   = (const float*)d_in[28];
    const float* lnb   = (const float*)d_in[29];
    float* out = (float*)d_out;

    xlstm_seq<<<dim3(256), dim3(256), 0, stream>>>(
        x, W_in, b_in, Wih, bih, Whh, Wq, bq, Wk, bk, Wv, bv,
        Wi, bi, Wf, bf, Wo, bo, Wp, bp,
        sWih, sbih, sWhh, sfb, aW1, ab1, aW2, ab2, lng, lnb, out);
}